// Round 3
// baseline (527.185 us; speedup 1.0000x reference)
//
#include <hip/hip_runtime.h>
#include <stdint.h>

#define B_ 128
#define T_ 1024
#define H_ 512
#define A_ 256
#define G_ 2128

typedef short s16x8 __attribute__((ext_vector_type(8)));
typedef float f32x4 __attribute__((ext_vector_type(4)));
typedef unsigned int u32;

__device__ inline unsigned short f2bf(float f) {
  unsigned u = __float_as_uint(f);
  u += 0x7fff + ((u >> 16) & 1);   // round-to-nearest-even
  return (unsigned short)(u >> 16);
}
__device__ inline unsigned pack2bf(float a, float b) {
  return ((unsigned)f2bf(b) << 16) | f2bf(a);
}
__device__ inline float bf_lo(unsigned u) { return __uint_as_float(u << 16); }
__device__ inline float bf_hi(unsigned u) { return __uint_as_float(u & 0xffff0000u); }
__device__ inline float fast_tanh(float x) {
  x = fminf(15.f, fmaxf(-15.f, x));
  float e = __expf(2.f * x);
  return (e - 1.f) * __builtin_amdgcn_rcpf(e + 1.f);
}
// async global->LDS, 16B per lane; LDS dest = uniform base + lane*16
__device__ inline void gl_lds16(const void* g, void* l) {
  __builtin_amdgcn_global_load_lds(
      (const __attribute__((address_space(1))) u32*)g,
      (__attribute__((address_space(3))) u32*)l, 16, 0, 0);
}

// K^T bf16 tiled [kb][a][k'], with 16B-group swizzle baked: group g of row a
// stored at position g^(a&3). 16 tiles of 256x32 shorts (16 KB each).
__global__ void prep_kt(const float* __restrict__ K,
                        unsigned short* __restrict__ khi) {
  int idx = blockIdx.x * 256 + threadIdx.x;   // h*256 + a
  int h = idx >> 8;
  int a = idx & 255;
  int kb = h >> 5, k = h & 31;
  int grp = k >> 3, sub = k & 7;
  khi[kb * 8192 + a * 32 + ((grp ^ (a & 3)) * 8) + sub] = f2bf(K[idx]);
}

// smiles fp32 [B,T,H] -> bf16 tiled [b][tb][kb][t'][swizzled 4x8 groups]
__global__ __launch_bounds__(256) void convert_k(const float* __restrict__ smiles,
                                                 unsigned short* __restrict__ smb) {
  int f = blockIdx.x * 256 + threadIdx.x;     // b*65536 + t*64 + h8
  int h8 = f & 63;
  int t = (f >> 6) & 1023;
  int b = f >> 16;
  const float* src = smiles + ((size_t)(b * 1024 + t)) * 512 + h8 * 8;
  float4 a0 = *reinterpret_cast<const float4*>(src);
  float4 a1 = *reinterpret_cast<const float4*>(src + 4);
  uint4 p;
  p.x = pack2bf(a0.x, a0.y); p.y = pack2bf(a0.z, a0.w);
  p.z = pack2bf(a1.x, a1.y); p.w = pack2bf(a1.z, a1.w);
  int tb = t >> 6, tp = t & 63, kb = h8 >> 2, g = h8 & 3;
  size_t dst = ((((size_t)b * 16 + tb) * 16 + kb) * 64 + tp) * 32
             + ((g ^ (tp & 3)) * 8);
  *reinterpret_cast<uint4*>(smb + dst) = p;
}

// gp[b][a] = w0 * sum_g genes[b,g]*Wg[g,a] + b_genes[a] + dense_bias[a]
__global__ __launch_bounds__(256) void gene_proj_k(
    const float* __restrict__ genes, const float* __restrict__ w0p,
    const float* __restrict__ Wg, const float* __restrict__ bg,
    const float* __restrict__ db, float* __restrict__ gp) {
  __shared__ float sg[532];
  int b = blockIdx.x;
  int gc = blockIdx.y;          // 0..3 chunks of 532
  int a = threadIdx.x;
  int g0 = gc * 532;
  for (int i = threadIdx.x; i < 532; i += 256) sg[i] = genes[(size_t)b * G_ + g0 + i];
  __syncthreads();
  float s = 0.f;
  #pragma unroll 8
  for (int g = 0; g < 532; ++g)
    s = fmaf(sg[g], Wg[(size_t)(g0 + g) * A_ + a], s);
  float val = w0p[0] * s;
  if (gc == 0) val += bg[a] + db[a];
  atomicAdd(&gp[b * A_ + a], val);
}

// Pass 1: block = 64 t x 256 a, 4 waves. Pure m97 K-loop: global_load_lds
// staging (swizzle baked in global layout), ds_read_b128 frags, 16 MFMA/wave.
__global__ __launch_bounds__(256, 4) void pass1(
    const unsigned short* __restrict__ smb, const unsigned short* __restrict__ khi,
    const float* __restrict__ gp, const float* __restrict__ v,
    float* __restrict__ xv) {
  __shared__ unsigned short sA[64 * 32];    // 4 KB
  __shared__ unsigned short sB[256 * 32];   // 16 KB
  __shared__ float sXV[64 * 4];

  const int tid = threadIdx.x;
  const int b = blockIdx.y;
  const int tb = blockIdx.x;
  const int lane = tid & 63;
  const int w = tid >> 6;
  const int n = lane & 15;
  const int q = lane >> 4;

  const unsigned short* Ab = smb + (((size_t)b * 16 + tb) * 16) * 2048;

  f32x4 acc[4][4];
  #pragma unroll
  for (int i = 0; i < 4; ++i)
    #pragma unroll
    for (int j = 0; j < 4; ++j)
      acc[i][j] = (f32x4){0.f, 0.f, 0.f, 0.f};

  for (int kb = 0; kb < 16; ++kb) {
    __syncthreads();
    // A tile: 2048 shorts; wave w stages shorts [w*512, w*512+512)
    gl_lds16(Ab + kb * 2048 + w * 512 + lane * 8, &sA[w * 512]);
    // B tile: 8192 shorts; wave w stages [w*2048, w*2048+2048)
    #pragma unroll
    for (int r = 0; r < 4; ++r)
      gl_lds16(khi + kb * 8192 + w * 2048 + r * 512 + lane * 8,
               &sB[w * 2048 + r * 512]);
    __syncthreads();

    s16x8 af[4], bh[4];
    const int sw = (q ^ (n & 3)) * 8;
    #pragma unroll
    for (int i = 0; i < 4; ++i)
      af[i] = *reinterpret_cast<const s16x8*>(&sA[(i * 16 + n) * 32 + sw]);
    #pragma unroll
    for (int j = 0; j < 4; ++j)
      bh[j] = *reinterpret_cast<const s16x8*>(&sB[(w * 64 + j * 16 + n) * 32 + sw]);
    #pragma unroll
    for (int i = 0; i < 4; ++i)
      #pragma unroll
      for (int j = 0; j < 4; ++j)
        acc[i][j] = __builtin_amdgcn_mfma_f32_16x16x32_bf16(af[i], bh[j], acc[i][j], 0, 0, 0);
  }

  // epilogue: sum_a v_a * tanh(gp + proj); D: t = q*4+r (+16i), a = n (+16j+64w)
  float vv[4], gg[4];
  #pragma unroll
  for (int j = 0; j < 4; ++j) {
    int a = w * 64 + j * 16 + n;
    vv[j] = v[a];
    gg[j] = gp[b * A_ + a];
  }
  #pragma unroll
  for (int i = 0; i < 4; ++i) {
    #pragma unroll
    for (int r = 0; r < 4; ++r) {
      float s = 0.f;
      #pragma unroll
      for (int j = 0; j < 4; ++j)
        s += vv[j] * fast_tanh(acc[i][j][r] + gg[j]);
      s += __shfl_xor(s, 1); s += __shfl_xor(s, 2);
      s += __shfl_xor(s, 4); s += __shfl_xor(s, 8);
      if (n == 0) sXV[(i * 16 + q * 4 + r) * 4 + w] = s;
    }
  }
  __syncthreads();
  if (tid < 64) {
    float* p = &sXV[tid * 4];
    xv[(size_t)b * T_ + tb * 64 + tid] = p[0] + p[1] + p[2] + p[3];
  }
}

__global__ __launch_bounds__(256) void softmax_k(const float* __restrict__ xv,
                                                 float* __restrict__ alphas) {
  __shared__ float red[8];
  int b = blockIdx.x, tid = threadIdx.x;
  float4 x = *reinterpret_cast<const float4*>(xv + b * T_ + tid * 4);
  float m = fmaxf(fmaxf(x.x, x.y), fmaxf(x.z, x.w));
  #pragma unroll
  for (int o = 1; o < 64; o <<= 1) m = fmaxf(m, __shfl_xor(m, o));
  if ((tid & 63) == 0) red[tid >> 6] = m;
  __syncthreads();
  m = fmaxf(fmaxf(red[0], red[1]), fmaxf(red[2], red[3]));
  float e0 = __expf(x.x - m), e1 = __expf(x.y - m);
  float e2 = __expf(x.z - m), e3 = __expf(x.w - m);
  float s = e0 + e1 + e2 + e3;
  #pragma unroll
  for (int o = 1; o < 64; o <<= 1) s += __shfl_xor(s, o);
  if ((tid & 63) == 0) red[4 + (tid >> 6)] = s;
  __syncthreads();
  s = red[4] + red[5] + red[6] + red[7];
  float inv = 1.f / s;
  float4 o4;
  o4.x = e0 * inv; o4.y = e1 * inv; o4.z = e2 * inv; o4.w = e3 * inv;
  *reinterpret_cast<float4*>(alphas + b * T_ + tid * 4) = o4;
}

// out[b,h] = sum_t smiles_bf16[b,t,h] * alphas[b,t], from tiled bf16 layout.
// block = (ts 0..3, b): covers tb in [ts*4, ts*4+4). thread: hg=tid&63 (kb,g),
// tq=tid>>6 (t-quarter within each tb's 64 rows).
__global__ __launch_bounds__(256) void pass3(const unsigned short* __restrict__ smb,
                                             const float* __restrict__ alphas,
                                             float* __restrict__ out) {
  __shared__ float red[3][64][8];     // 6 KB
  int b = blockIdx.y, ts = blockIdx.x;
  int tid = threadIdx.x;
  int hg = tid & 63, tq = tid >> 6;
  int kb = hg >> 2, g = hg & 3;
  float acc[8] = {0.f, 0.f, 0.f, 0.f, 0.f, 0.f, 0.f, 0.f};
  for (int tb = ts * 4; tb < ts * 4 + 4; ++tb) {
    const unsigned short* tile = smb + (((size_t)b * 16 + tb) * 16 + kb) * 2048;
    const float* al = alphas + b * T_ + tb * 64;
    #pragma unroll 4
    for (int tt = 0; tt < 16; ++tt) {
      int tp = tq * 16 + tt;
      float a = al[tp];
      uint4 d = *reinterpret_cast<const uint4*>(tile + tp * 32 + ((g ^ (tp & 3)) * 8));
      acc[0] = fmaf(a, bf_lo(d.x), acc[0]); acc[1] = fmaf(a, bf_hi(d.x), acc[1]);
      acc[2] = fmaf(a, bf_lo(d.y), acc[2]); acc[3] = fmaf(a, bf_hi(d.y), acc[3]);
      acc[4] = fmaf(a, bf_lo(d.z), acc[4]); acc[5] = fmaf(a, bf_hi(d.z), acc[5]);
      acc[6] = fmaf(a, bf_lo(d.w), acc[6]); acc[7] = fmaf(a, bf_hi(d.w), acc[7]);
    }
  }
  if (tq) {
    #pragma unroll
    for (int e = 0; e < 8; ++e) red[tq - 1][hg][e] = acc[e];
  }
  __syncthreads();
  if (tq == 0) {
    float* op = out + (size_t)b * H_ + kb * 32 + g * 8;
    #pragma unroll
    for (int e = 0; e < 8; ++e)
      atomicAdd(op + e, acc[e] + red[0][hg][e] + red[1][hg][e] + red[2][hg][e]);
  }
}

extern "C" void kernel_launch(void* const* d_in, const int* in_sizes, int n_in,
                              void* d_out, int out_size, void* d_ws, size_t ws_size,
                              hipStream_t stream) {
  const float* genes  = (const float*)d_in[0];
  const float* smiles = (const float*)d_in[1];
  const float* w0     = (const float*)d_in[2];
  const float* wg     = (const float*)d_in[3];
  const float* bg     = (const float*)d_in[4];
  const float* dk     = (const float*)d_in[5];
  const float* db     = (const float*)d_in[6];
  const float* v      = (const float*)d_in[7];
  float* out = (float*)d_out;            // [B,H] output then [B,T] alphas
  char* ws = (char*)d_ws;
  float* gp = (float*)ws;                                    // @0, 128 KB
  unsigned short* khi = (unsigned short*)(ws + 131072);      // 512 KB
  float* xv = (float*)(ws + 131072 + 262144);                // 512 KB
  unsigned short* smb = (unsigned short*)(ws + (1 << 20));   // 128 MB
  float* alphas = out + B_ * H_;

  hipMemsetAsync(gp, 0, B_ * A_ * sizeof(float), stream);
  hipMemsetAsync(out, 0, B_ * H_ * sizeof(float), stream);
  prep_kt<<<512, 256, 0, stream>>>(dk, khi);
  convert_k<<<32768, 256, 0, stream>>>(smiles, smb);
  gene_proj_k<<<dim3(B_, 4), 256, 0, stream>>>(genes, w0, wg, bg, db, gp);
  pass1<<<dim3(16, B_), 256, 0, stream>>>(smb, khi, gp, v, xv);
  softmax_k<<<B_, 256, 0, stream>>>(xv, alphas);
  pass3<<<dim3(4, B_), 256, 0, stream>>>(smb, alphas, out);
}

// Round 4
// 507.279 us; speedup vs baseline: 1.0392x; 1.0392x over previous
//
#include <hip/hip_runtime.h>
#include <stdint.h>

#define B_ 128
#define T_ 1024
#define H_ 512
#define A_ 256
#define G_ 2128

typedef short s16x8 __attribute__((ext_vector_type(8)));
typedef float f32x4 __attribute__((ext_vector_type(4)));
typedef unsigned int u32;

__device__ inline unsigned short f2bf(float f) {
  unsigned u = __float_as_uint(f);
  u += 0x7fff + ((u >> 16) & 1);   // round-to-nearest-even
  return (unsigned short)(u >> 16);
}
__device__ inline unsigned pack2bf(float a, float b) {
  return ((unsigned)f2bf(b) << 16) | f2bf(a);
}
__device__ inline float bf_lo(unsigned u) { return __uint_as_float(u << 16); }
__device__ inline float bf_hi(unsigned u) { return __uint_as_float(u & 0xffff0000u); }
__device__ inline float fast_tanh(float x) {
  x = fminf(15.f, fmaxf(-15.f, x));
  float e = __expf(2.f * x);
  return (e - 1.f) * __builtin_amdgcn_rcpf(e + 1.f);
}
// async global->LDS, 16B per lane; LDS dest = uniform base + lane*16
__device__ inline void gl_lds16(const void* g, void* l) {
  __builtin_amdgcn_global_load_lds(
      (const __attribute__((address_space(1))) u32*)g,
      (__attribute__((address_space(3))) u32*)l, 16, 0, 0);
}

// K^T bf16 tiled [kb][a][k'], 16B-group swizzle baked: group g of row a at g^(a&3).
__global__ void prep_kt(const float* __restrict__ K,
                        unsigned short* __restrict__ khi) {
  int idx = blockIdx.x * 256 + threadIdx.x;   // h*256 + a
  int h = idx >> 8;
  int a = idx & 255;
  int kb = h >> 5, k = h & 31;
  int grp = k >> 3, sub = k & 7;
  khi[kb * 8192 + a * 32 + ((grp ^ (a & 3)) * 8) + sub] = f2bf(K[idx]);
}

// gp[b][a] = w0 * sum_g genes[b,g]*Wg[g,a] + b_genes[a] + dense_bias[a]
__global__ __launch_bounds__(256) void gene_proj_k(
    const float* __restrict__ genes, const float* __restrict__ w0p,
    const float* __restrict__ Wg, const float* __restrict__ bg,
    const float* __restrict__ db, float* __restrict__ gp) {
  __shared__ float sg[532];
  int b = blockIdx.x;
  int gc = blockIdx.y;          // 0..3 chunks of 532
  int a = threadIdx.x;
  int g0 = gc * 532;
  for (int i = threadIdx.x; i < 532; i += 256) sg[i] = genes[(size_t)b * G_ + g0 + i];
  __syncthreads();
  float s = 0.f;
  #pragma unroll 8
  for (int g = 0; g < 532; ++g)
    s = fmaf(sg[g], Wg[(size_t)(g0 + g) * A_ + a], s);
  float val = w0p[0] * s;
  if (gc == 0) val += bg[a] + db[a];
  atomicAdd(&gp[b * A_ + a], val);
}

// Pass 1 (fused convert + GEMM): block = 64 t x 256 a, 4 waves.
// A: fp32 smiles read coalesced, packed to bf16 in-register, written to LDS
// (swizzled) AND to global smb (tile-major, for pass3). B: global_load_lds
// from swizzle-baked khi. Next A-chunk register-prefetched under the MFMAs.
__global__ __launch_bounds__(256, 4) void pass1(
    const float* __restrict__ smiles, const unsigned short* __restrict__ khi,
    unsigned short* __restrict__ smb, const float* __restrict__ gp,
    const float* __restrict__ v, float* __restrict__ xv) {
  __shared__ unsigned short sA[64 * 32];    // 4 KB
  __shared__ unsigned short sB[256 * 32];   // 16 KB
  __shared__ float sXV[64 * 4];

  const int tid = threadIdx.x;
  const int b = blockIdx.y;
  const int tb = blockIdx.x;
  const int lane = tid & 63;
  const int w = tid >> 6;
  const int n = lane & 15;
  const int q = lane >> 4;

  const int ar = tid >> 2;      // staging row (t')
  const int ac = tid & 3;       // staging 16B-group
  const int swg = (ac ^ (ar & 3)) * 8;
  const float* asrc = smiles + ((size_t)(b * 1024 + tb * 64 + ar)) * 512 + ac * 8;
  unsigned short* adst =
      smb + ((((size_t)(b * 16 + tb)) * 16 * 64 + ar) * 32) + swg;  // + kb*2048

  f32x4 acc[4][4];
  #pragma unroll
  for (int i = 0; i < 4; ++i)
    #pragma unroll
    for (int j = 0; j < 4; ++j)
      acc[i][j] = (f32x4){0.f, 0.f, 0.f, 0.f};

  float4 f0 = *reinterpret_cast<const float4*>(asrc);
  float4 f1 = *reinterpret_cast<const float4*>(asrc + 4);

  for (int kb = 0; kb < 16; ++kb) {
    __syncthreads();
    // stage A (already in regs), keep a bf16 copy in global for pass3
    uint4 p;
    p.x = pack2bf(f0.x, f0.y); p.y = pack2bf(f0.z, f0.w);
    p.z = pack2bf(f1.x, f1.y); p.w = pack2bf(f1.z, f1.w);
    *reinterpret_cast<uint4*>(&sA[ar * 32 + swg]) = p;
    *reinterpret_cast<uint4*>(adst + kb * 2048) = p;
    // stage B: wave w fills sB[w*2048 .. +2048)
    #pragma unroll
    for (int r = 0; r < 4; ++r)
      gl_lds16(khi + kb * 8192 + w * 2048 + r * 512 + lane * 8,
               &sB[w * 2048 + r * 512]);
    __syncthreads();
    // prefetch next A chunk (hides under MFMAs)
    if (kb < 15) {
      f0 = *reinterpret_cast<const float4*>(asrc + (kb + 1) * 32);
      f1 = *reinterpret_cast<const float4*>(asrc + (kb + 1) * 32 + 4);
    }

    s16x8 af[4], bh[4];
    const int sw = (q ^ (n & 3)) * 8;
    #pragma unroll
    for (int i = 0; i < 4; ++i)
      af[i] = *reinterpret_cast<const s16x8*>(&sA[(i * 16 + n) * 32 + sw]);
    #pragma unroll
    for (int j = 0; j < 4; ++j)
      bh[j] = *reinterpret_cast<const s16x8*>(&sB[(w * 64 + j * 16 + n) * 32 + sw]);
    #pragma unroll
    for (int i = 0; i < 4; ++i)
      #pragma unroll
      for (int j = 0; j < 4; ++j)
        acc[i][j] = __builtin_amdgcn_mfma_f32_16x16x32_bf16(af[i], bh[j], acc[i][j], 0, 0, 0);
  }

  // epilogue: sum_a v_a * tanh(gp + proj); D: t = q*4+r (+16i), a = n (+16j+64w)
  float vv[4], gg[4];
  #pragma unroll
  for (int j = 0; j < 4; ++j) {
    int a = w * 64 + j * 16 + n;
    vv[j] = v[a];
    gg[j] = gp[b * A_ + a];
  }
  #pragma unroll
  for (int i = 0; i < 4; ++i) {
    #pragma unroll
    for (int r = 0; r < 4; ++r) {
      float s = 0.f;
      #pragma unroll
      for (int j = 0; j < 4; ++j)
        s += vv[j] * fast_tanh(acc[i][j][r] + gg[j]);
      s += __shfl_xor(s, 1); s += __shfl_xor(s, 2);
      s += __shfl_xor(s, 4); s += __shfl_xor(s, 8);
      if (n == 0) sXV[(i * 16 + q * 4 + r) * 4 + w] = s;
    }
  }
  __syncthreads();
  if (tid < 64) {
    float* p = &sXV[tid * 4];
    xv[(size_t)b * T_ + tb * 64 + tid] = p[0] + p[1] + p[2] + p[3];
  }
}

__global__ __launch_bounds__(256) void softmax_k(const float* __restrict__ xv,
                                                 float* __restrict__ alphas) {
  __shared__ float red[8];
  int b = blockIdx.x, tid = threadIdx.x;
  float4 x = *reinterpret_cast<const float4*>(xv + b * T_ + tid * 4);
  float m = fmaxf(fmaxf(x.x, x.y), fmaxf(x.z, x.w));
  #pragma unroll
  for (int o = 1; o < 64; o <<= 1) m = fmaxf(m, __shfl_xor(m, o));
  if ((tid & 63) == 0) red[tid >> 6] = m;
  __syncthreads();
  m = fmaxf(fmaxf(red[0], red[1]), fmaxf(red[2], red[3]));
  float e0 = __expf(x.x - m), e1 = __expf(x.y - m);
  float e2 = __expf(x.z - m), e3 = __expf(x.w - m);
  float s = e0 + e1 + e2 + e3;
  #pragma unroll
  for (int o = 1; o < 64; o <<= 1) s += __shfl_xor(s, o);
  if ((tid & 63) == 0) red[4 + (tid >> 6)] = s;
  __syncthreads();
  s = red[4] + red[5] + red[6] + red[7];
  float inv = 1.f / s;
  float4 o4;
  o4.x = e0 * inv; o4.y = e1 * inv; o4.z = e2 * inv; o4.w = e3 * inv;
  *reinterpret_cast<float4*>(alphas + b * T_ + tid * 4) = o4;
}

// out[b,h] = sum_t smiles_bf16[b,t,h] * alphas[b,t], from tiled bf16 layout.
__global__ __launch_bounds__(256) void pass3(const unsigned short* __restrict__ smb,
                                             const float* __restrict__ alphas,
                                             float* __restrict__ out) {
  __shared__ float red[3][64][8];     // 6 KB
  int b = blockIdx.y, ts = blockIdx.x;
  int tid = threadIdx.x;
  int hg = tid & 63, tq = tid >> 6;
  int kb = hg >> 2, g = hg & 3;
  float acc[8] = {0.f, 0.f, 0.f, 0.f, 0.f, 0.f, 0.f, 0.f};
  for (int tb = ts * 4; tb < ts * 4 + 4; ++tb) {
    const unsigned short* tile = smb + (((size_t)b * 16 + tb) * 16 + kb) * 2048;
    const float* al = alphas + b * T_ + tb * 64;
    #pragma unroll 4
    for (int tt = 0; tt < 16; ++tt) {
      int tp = tq * 16 + tt;
      float a = al[tp];
      uint4 d = *reinterpret_cast<const uint4*>(tile + tp * 32 + ((g ^ (tp & 3)) * 8));
      acc[0] = fmaf(a, bf_lo(d.x), acc[0]); acc[1] = fmaf(a, bf_hi(d.x), acc[1]);
      acc[2] = fmaf(a, bf_lo(d.y), acc[2]); acc[3] = fmaf(a, bf_hi(d.y), acc[3]);
      acc[4] = fmaf(a, bf_lo(d.z), acc[4]); acc[5] = fmaf(a, bf_hi(d.z), acc[5]);
      acc[6] = fmaf(a, bf_lo(d.w), acc[6]); acc[7] = fmaf(a, bf_hi(d.w), acc[7]);
    }
  }
  if (tq) {
    #pragma unroll
    for (int e = 0; e < 8; ++e) red[tq - 1][hg][e] = acc[e];
  }
  __syncthreads();
  if (tq == 0) {
    float* op = out + (size_t)b * H_ + kb * 32 + g * 8;
    #pragma unroll
    for (int e = 0; e < 8; ++e)
      atomicAdd(op + e, acc[e] + red[0][hg][e] + red[1][hg][e] + red[2][hg][e]);
  }
}

extern "C" void kernel_launch(void* const* d_in, const int* in_sizes, int n_in,
                              void* d_out, int out_size, void* d_ws, size_t ws_size,
                              hipStream_t stream) {
  const float* genes  = (const float*)d_in[0];
  const float* smiles = (const float*)d_in[1];
  const float* w0     = (const float*)d_in[2];
  const float* wg     = (const float*)d_in[3];
  const float* bg     = (const float*)d_in[4];
  const float* dk     = (const float*)d_in[5];
  const float* db     = (const float*)d_in[6];
  const float* v      = (const float*)d_in[7];
  float* out = (float*)d_out;            // [B,H] output then [B,T] alphas
  char* ws = (char*)d_ws;
  float* gp = (float*)ws;                                    // @0, 128 KB
  unsigned short* khi = (unsigned short*)(ws + 131072);      // 256 KB
  float* xv = (float*)(ws + 131072 + 262144);                // 512 KB
  unsigned short* smb = (unsigned short*)(ws + (1 << 20));   // 128 MB
  float* alphas = out + B_ * H_;

  hipMemsetAsync(gp, 0, B_ * A_ * sizeof(float), stream);
  hipMemsetAsync(out, 0, B_ * H_ * sizeof(float), stream);
  prep_kt<<<512, 256, 0, stream>>>(dk, khi);
  gene_proj_k<<<dim3(B_, 4), 256, 0, stream>>>(genes, w0, wg, bg, db, gp);
  pass1<<<dim3(16, B_), 256, 0, stream>>>(smiles, khi, smb, gp, v, xv);
  softmax_k<<<B_, 256, 0, stream>>>(xv, alphas);
  pass3<<<dim3(4, B_), 256, 0, stream>>>(smb, alphas, out);
}

// Round 5
// 499.461 us; speedup vs baseline: 1.0555x; 1.0157x over previous
//
#include <hip/hip_runtime.h>
#include <stdint.h>

#define B_ 128
#define T_ 1024
#define H_ 512
#define A_ 256
#define G_ 2128

typedef short s16x8 __attribute__((ext_vector_type(8)));
typedef float f32x4 __attribute__((ext_vector_type(4)));
typedef unsigned int u32;

__device__ inline unsigned short f2bf(float f) {
  unsigned u = __float_as_uint(f);
  u += 0x7fff + ((u >> 16) & 1);   // round-to-nearest-even
  return (unsigned short)(u >> 16);
}
__device__ inline unsigned pack2bf(float a, float b) {
  return ((unsigned)f2bf(b) << 16) | f2bf(a);
}
__device__ inline float bf_lo(unsigned u) { return __uint_as_float(u << 16); }
__device__ inline float bf_hi(unsigned u) { return __uint_as_float(u & 0xffff0000u); }
__device__ inline float fast_tanh(float x) {
  x = fminf(15.f, fmaxf(-15.f, x));
  float e = __expf(2.f * x);
  return (e - 1.f) * __builtin_amdgcn_rcpf(e + 1.f);
}
// async global->LDS, 16B per lane; LDS dest = uniform base + lane*16
__device__ inline void gl_lds16(const void* g, void* l) {
  __builtin_amdgcn_global_load_lds(
      (const __attribute__((address_space(1))) u32*)g,
      (__attribute__((address_space(3))) u32*)l, 16, 0, 0);
}

// K^T bf16 tiled [kb][a][k'], 16B-group swizzle baked: group g of row a at g^(a&3).
__global__ void prep_kt(const float* __restrict__ K,
                        unsigned short* __restrict__ khi) {
  int idx = blockIdx.x * 256 + threadIdx.x;   // h*256 + a
  int h = idx >> 8;
  int a = idx & 255;
  int kb = h >> 5, k = h & 31;
  int grp = k >> 3, sub = k & 7;
  khi[kb * 8192 + a * 32 + ((grp ^ (a & 3)) * 8) + sub] = f2bf(K[idx]);
}

// gp4[gc][b][a] = partial of w0 * sum_g genes[b,g]*Wg[g,a]; gc==0 adds biases.
__global__ __launch_bounds__(256) void gene_proj_k(
    const float* __restrict__ genes, const float* __restrict__ w0p,
    const float* __restrict__ Wg, const float* __restrict__ bg,
    const float* __restrict__ db, float* __restrict__ gp4) {
  __shared__ float sg[532];
  int b = blockIdx.x;
  int gc = blockIdx.y;          // 0..3 chunks of 532
  int a = threadIdx.x;
  int g0 = gc * 532;
  for (int i = threadIdx.x; i < 532; i += 256) sg[i] = genes[(size_t)b * G_ + g0 + i];
  __syncthreads();
  float s = 0.f;
  #pragma unroll 8
  for (int g = 0; g < 532; ++g)
    s = fmaf(sg[g], Wg[(size_t)(g0 + g) * A_ + a], s);
  float val = w0p[0] * s;
  if (gc == 0) val += bg[a] + db[a];
  gp4[(gc * B_ + b) * A_ + a] = val;
}

// Pass 1 (fused convert + GEMM): block = 128 t x 256 a, 4 waves.
// Wave w: 8 i-frags (t) x 4 j-frags (a in [w*64,w*64+64)) = 32 MFMA / K-step.
// A: fp32 smiles read coalesced, bf16-packed in-register, stored to LDS
// (swizzled) AND to global smb (tile-major, for pass3). B: global_load_lds.
__global__ __launch_bounds__(256, 2) void pass1(
    const float* __restrict__ smiles, const unsigned short* __restrict__ khi,
    unsigned short* __restrict__ smb, const float* __restrict__ gp4,
    const float* __restrict__ v, float* __restrict__ xv) {
  __shared__ unsigned short sA[128 * 32];   // 8 KB
  __shared__ unsigned short sB[256 * 32];   // 16 KB
  __shared__ float sXV[128 * 4];            // 2 KB

  const int tid = threadIdx.x;
  const int b = blockIdx.y;
  const int tb = blockIdx.x;                // 0..7 (128-t tiles)
  const int lane = tid & 63;
  const int w = tid >> 6;
  const int n = lane & 15;
  const int q = lane >> 4;

  // A staging: thread -> row ar (0..127), half-row (16 fp32)
  const int ar = tid >> 1;
  const int half = tid & 1;
  const int g0 = half * 2;                  // groups {0,1} or {2,3}
  const int s0 = (g0 ^ (ar & 3)) * 8;
  const int s1 = ((g0 + 1) ^ (ar & 3)) * 8;
  const float* asrc = smiles + ((size_t)(b * 1024 + tb * 128 + ar)) * 512 + half * 16;
  unsigned short* adst = smb + (((size_t)(b * 8 + tb)) * 16) * 4096 + ar * 32;

  f32x4 acc[8][4];
  #pragma unroll
  for (int i = 0; i < 8; ++i)
    #pragma unroll
    for (int j = 0; j < 4; ++j)
      acc[i][j] = (f32x4){0.f, 0.f, 0.f, 0.f};

  float4 f0 = *reinterpret_cast<const float4*>(asrc);
  float4 f1 = *reinterpret_cast<const float4*>(asrc + 4);
  float4 f2 = *reinterpret_cast<const float4*>(asrc + 8);
  float4 f3 = *reinterpret_cast<const float4*>(asrc + 12);

  for (int kb = 0; kb < 16; ++kb) {
    __syncthreads();
    // stage A (in regs) to LDS + keep bf16 copy in global for pass3
    uint4 p0, p1;
    p0.x = pack2bf(f0.x, f0.y); p0.y = pack2bf(f0.z, f0.w);
    p0.z = pack2bf(f1.x, f1.y); p0.w = pack2bf(f1.z, f1.w);
    p1.x = pack2bf(f2.x, f2.y); p1.y = pack2bf(f2.z, f2.w);
    p1.z = pack2bf(f3.x, f3.y); p1.w = pack2bf(f3.z, f3.w);
    *reinterpret_cast<uint4*>(&sA[ar * 32 + s0]) = p0;
    *reinterpret_cast<uint4*>(&sA[ar * 32 + s1]) = p1;
    *reinterpret_cast<uint4*>(adst + kb * 4096 + s0) = p0;
    *reinterpret_cast<uint4*>(adst + kb * 4096 + s1) = p1;
    // stage B: wave w fills sB[w*2048 .. +2048)
    #pragma unroll
    for (int r = 0; r < 4; ++r)
      gl_lds16(khi + kb * 8192 + w * 2048 + r * 512 + lane * 8,
               &sB[w * 2048 + r * 512]);
    __syncthreads();
    // prefetch next A chunk (hides under MFMAs)
    if (kb < 15) {
      f0 = *reinterpret_cast<const float4*>(asrc + (kb + 1) * 32);
      f1 = *reinterpret_cast<const float4*>(asrc + (kb + 1) * 32 + 4);
      f2 = *reinterpret_cast<const float4*>(asrc + (kb + 1) * 32 + 8);
      f3 = *reinterpret_cast<const float4*>(asrc + (kb + 1) * 32 + 12);
    }

    s16x8 af[8], bh[4];
    const int sw = (q ^ (n & 3)) * 8;
    #pragma unroll
    for (int j = 0; j < 4; ++j)
      bh[j] = *reinterpret_cast<const s16x8*>(&sB[(w * 64 + j * 16 + n) * 32 + sw]);
    #pragma unroll
    for (int i = 0; i < 8; ++i)
      af[i] = *reinterpret_cast<const s16x8*>(&sA[(i * 16 + n) * 32 + sw]);
    #pragma unroll
    for (int i = 0; i < 8; ++i)
      #pragma unroll
      for (int j = 0; j < 4; ++j)
        acc[i][j] = __builtin_amdgcn_mfma_f32_16x16x32_bf16(af[i], bh[j], acc[i][j], 0, 0, 0);
  }

  // epilogue: sum_a v_a * tanh(gp + proj); D: t = q*4+r (+16i), a = n (+16j+64w)
  float vv[4], gg[4];
  #pragma unroll
  for (int j = 0; j < 4; ++j) {
    int a = w * 64 + j * 16 + n;
    int idx = b * A_ + a;
    vv[j] = v[a];
    gg[j] = gp4[idx] + gp4[B_ * A_ + idx] + gp4[2 * B_ * A_ + idx] +
            gp4[3 * B_ * A_ + idx];
  }
  #pragma unroll
  for (int i = 0; i < 8; ++i) {
    #pragma unroll
    for (int r = 0; r < 4; ++r) {
      float s = 0.f;
      #pragma unroll
      for (int j = 0; j < 4; ++j)
        s += vv[j] * fast_tanh(acc[i][j][r] + gg[j]);
      s += __shfl_xor(s, 1); s += __shfl_xor(s, 2);
      s += __shfl_xor(s, 4); s += __shfl_xor(s, 8);
      if (n == 0) sXV[(i * 16 + q * 4 + r) * 4 + w] = s;
    }
  }
  __syncthreads();
  if (tid < 128) {
    float* p = &sXV[tid * 4];
    xv[(size_t)b * T_ + tb * 128 + tid] = p[0] + p[1] + p[2] + p[3];
  }
}

__global__ __launch_bounds__(256) void softmax_k(const float* __restrict__ xv,
                                                 float* __restrict__ alphas) {
  __shared__ float red[8];
  int b = blockIdx.x, tid = threadIdx.x;
  float4 x = *reinterpret_cast<const float4*>(xv + b * T_ + tid * 4);
  float m = fmaxf(fmaxf(x.x, x.y), fmaxf(x.z, x.w));
  #pragma unroll
  for (int o = 1; o < 64; o <<= 1) m = fmaxf(m, __shfl_xor(m, o));
  if ((tid & 63) == 0) red[tid >> 6] = m;
  __syncthreads();
  m = fmaxf(fmaxf(red[0], red[1]), fmaxf(red[2], red[3]));
  float e0 = __expf(x.x - m), e1 = __expf(x.y - m);
  float e2 = __expf(x.z - m), e3 = __expf(x.w - m);
  float s = e0 + e1 + e2 + e3;
  #pragma unroll
  for (int o = 1; o < 64; o <<= 1) s += __shfl_xor(s, o);
  if ((tid & 63) == 0) red[4 + (tid >> 6)] = s;
  __syncthreads();
  s = red[4] + red[5] + red[6] + red[7];
  float inv = 1.f / s;
  float4 o4;
  o4.x = e0 * inv; o4.y = e1 * inv; o4.z = e2 * inv; o4.w = e3 * inv;
  *reinterpret_cast<float4*>(alphas + b * T_ + tid * 4) = o4;
}

// out[b,h] = sum_t smiles_bf16[b,t,h] * alphas[b,t], tiled layout
// [b][tb(8)][kb(16)][tp(128)][32 shorts swizzled].
__global__ __launch_bounds__(256) void pass3(const unsigned short* __restrict__ smb,
                                             const float* __restrict__ alphas,
                                             float* __restrict__ out) {
  __shared__ float red[3][64][8];     // 6 KB
  int b = blockIdx.y, ts = blockIdx.x;
  int tid = threadIdx.x;
  int hg = tid & 63, tq = tid >> 6;
  int kb = hg >> 2, g = hg & 3;
  float acc[8] = {0.f, 0.f, 0.f, 0.f, 0.f, 0.f, 0.f, 0.f};
  for (int tb = ts * 2; tb < ts * 2 + 2; ++tb) {
    const unsigned short* tile = smb + (((size_t)b * 8 + tb) * 16 + kb) * 4096;
    const float* al = alphas + b * T_ + tb * 128;
    #pragma unroll 4
    for (int tt = 0; tt < 32; ++tt) {
      int tp = tq * 32 + tt;
      float a = al[tp];
      uint4 d = *reinterpret_cast<const uint4*>(tile + tp * 32 + ((g ^ (tp & 3)) * 8));
      acc[0] = fmaf(a, bf_lo(d.x), acc[0]); acc[1] = fmaf(a, bf_hi(d.x), acc[1]);
      acc[2] = fmaf(a, bf_lo(d.y), acc[2]); acc[3] = fmaf(a, bf_hi(d.y), acc[3]);
      acc[4] = fmaf(a, bf_lo(d.z), acc[4]); acc[5] = fmaf(a, bf_hi(d.z), acc[5]);
      acc[6] = fmaf(a, bf_lo(d.w), acc[6]); acc[7] = fmaf(a, bf_hi(d.w), acc[7]);
    }
  }
  if (tq) {
    #pragma unroll
    for (int e = 0; e < 8; ++e) red[tq - 1][hg][e] = acc[e];
  }
  __syncthreads();
  if (tq == 0) {
    float* op = out + (size_t)b * H_ + kb * 32 + g * 8;
    #pragma unroll
    for (int e = 0; e < 8; ++e)
      atomicAdd(op + e, acc[e] + red[0][hg][e] + red[1][hg][e] + red[2][hg][e]);
  }
}

extern "C" void kernel_launch(void* const* d_in, const int* in_sizes, int n_in,
                              void* d_out, int out_size, void* d_ws, size_t ws_size,
                              hipStream_t stream) {
  const float* genes  = (const float*)d_in[0];
  const float* smiles = (const float*)d_in[1];
  const float* w0     = (const float*)d_in[2];
  const float* wg     = (const float*)d_in[3];
  const float* bg     = (const float*)d_in[4];
  const float* dk     = (const float*)d_in[5];
  const float* db     = (const float*)d_in[6];
  const float* v      = (const float*)d_in[7];
  float* out = (float*)d_out;            // [B,H] output then [B,T] alphas
  char* ws = (char*)d_ws;
  float* gp4 = (float*)ws;                                   // 512 KB (4 partials)
  unsigned short* khi = (unsigned short*)(ws + 524288);      // 256 KB
  float* xv = (float*)(ws + 524288 + 262144);                // 512 KB
  unsigned short* smb = (unsigned short*)(ws + (2 << 20));   // 128 MB
  float* alphas = out + B_ * H_;

  hipMemsetAsync(out, 0, B_ * H_ * sizeof(float), stream);
  prep_kt<<<512, 256, 0, stream>>>(dk, khi);
  gene_proj_k<<<dim3(B_, 4), 256, 0, stream>>>(genes, w0, wg, bg, db, gp4);
  pass1<<<dim3(8, B_), 256, 0, stream>>>(smiles, khi, smb, gp4, v, xv);
  softmax_k<<<B_, 256, 0, stream>>>(xv, alphas);
  pass3<<<dim3(4, B_), 256, 0, stream>>>(smb, alphas, out);
}